// Round 6
// baseline (140.232 us; speedup 1.0000x reference)
//
#include <hip/hip_runtime.h>

#define BS 32
#define NA 512
#define ID 128
#define NH 8
#define HD 64
#define NHD 512   // NH*HD
#define NEG 0.2f
#define NC 32     // scalar chunk count (G=16) for zps/znp
#define CH 16
#define NW 8      // waves per k2 block (512 threads)
#define BPAD 136  // B LDS col stride (bf16 elems): 272B -> 2-way bank alias (free)

typedef short bf16x8 __attribute__((ext_vector_type(8)));
typedef float f32x4 __attribute__((ext_vector_type(4)));

__device__ inline unsigned f2bf_bits(float x) {   // RNE f32 -> bf16 bits
  unsigned u = __float_as_uint(x);
  return (u + 0x7FFFu + ((u >> 16) & 1u)) >> 16;
}

// split 8 floats into bf16 hi + bf16 lo fragments (static indices only)
__device__ inline void split8(const float4& x, const float4& y,
                              bf16x8& hi, bf16x8& lo) {
  float f[8] = {x.x, x.y, x.z, x.w, y.x, y.y, y.z, y.w};
  #pragma unroll
  for (int j = 0; j < 8; ++j) {
    unsigned hb = f2bf_bits(f[j]);
    float r = f[j] - __uint_as_float(hb << 16);
    unsigned lb = f2bf_bits(r);
    hi[j] = (short)hb;
    lo[j] = (short)lb;
  }
}

// K1 (MFMA): hp = h @ W via split-bf16 3-pass (hi*hi + hi*lo + lo*hi), fp32
// accumulate. Unchanged from R4 (verified). Writes hp into d_ws (the harness
// poison-fills d_ws every iter regardless of use — R3 proved it — so the
// workspace is free and separates hp from out, making sweep re-reads safe).
__global__ __launch_bounds__(256, 4) void k1_mfma(
    const float* __restrict__ h, const float* __restrict__ W,
    float* __restrict__ hp) {
  __shared__ unsigned short Bhi[64 * BPAD];
  __shared__ unsigned short Blo[64 * BPAD];

  int blk = blockIdx.x;
  int mt = blk >> 3;            // M-tile 0..127 (128 rows each)
  int n0 = (blk & 7) * 64;      // N-tile start col
  int m0 = mt * 128;
  int b = mt >> 2;              // batch
  int nbase = (mt & 3) * 128;   // agent-row base within batch
  int head = n0 >> 6;
  int t = threadIdx.x;
  int lane = t & 63, w = t >> 6;
  int q = lane >> 4, ml = lane & 15;

  // ---- stage W[n0..n0+63] split+transposed into LDS ----
  {
    int c = t & 63, kq = t >> 6;
    const float* wsrc = W + (size_t)kq * 32 * NHD + n0 + c;
    #pragma unroll 4
    for (int kk = 0; kk < 32; ++kk) {
      int k = kq * 32 + kk;
      float x = wsrc[(size_t)kk * NHD];
      unsigned hb = f2bf_bits(x);
      float r = x - __uint_as_float(hb << 16);
      Bhi[c * BPAD + k] = (unsigned short)hb;
      Blo[c * BPAD + k] = (unsigned short)f2bf_bits(r);
    }
  }
  __syncthreads();

  f32x4 acc[2][4];
  #pragma unroll
  for (int mf = 0; mf < 2; ++mf)
    #pragma unroll
    for (int nf = 0; nf < 4; ++nf)
      acc[mf][nf] = (f32x4){0.f, 0.f, 0.f, 0.f};

  const float* A0 = h + (size_t)(m0 + w * 32 + ml) * ID;

  #pragma unroll
  for (int ks = 0; ks < 4; ++ks) {
    int ko = ks * 32 + q * 8;          // my k mapping: k = 8*quarter + elem
    bf16x8 ah[2], al[2];
    #pragma unroll
    for (int mf = 0; mf < 2; ++mf) {
      const float* ap = A0 + mf * 16 * ID + ko;
      float4 f0 = *(const float4*)ap;
      float4 f1 = *(const float4*)(ap + 4);
      split8(f0, f1, ah[mf], al[mf]);
    }
    #pragma unroll
    for (int nf = 0; nf < 4; ++nf) {
      int bo = (nf * 16 + ml) * BPAD + ko;   // same k mapping on B side
      bf16x8 bh = *(const bf16x8*)&Bhi[bo];
      bf16x8 bl = *(const bf16x8*)&Blo[bo];
      #pragma unroll
      for (int mf = 0; mf < 2; ++mf) {
        acc[mf][nf] = __builtin_amdgcn_mfma_f32_16x16x32_bf16(ah[mf], bh, acc[mf][nf], 0, 0, 0);
        acc[mf][nf] = __builtin_amdgcn_mfma_f32_16x16x32_bf16(ah[mf], bl, acc[mf][nf], 0, 0, 0);
        acc[mf][nf] = __builtin_amdgcn_mfma_f32_16x16x32_bf16(al[mf], bh, acc[mf][nf], 0, 0, 0);
      }
    }
  }

  // ---- epilogue: D layout col=lane&15, row=4*(lane>>4)+reg (HW-verified) ----
  {
    float* ob = hp + (((size_t)b * NH + head) * NA + nbase + w * 32) * HD + ml;
    #pragma unroll
    for (int mf = 0; mf < 2; ++mf)
      #pragma unroll
      for (int nf = 0; nf < 4; ++nf)
        #pragma unroll
        for (int r = 0; r < 4; ++r)
          ob[(size_t)(mf * 16 + q * 4 + r) * HD + nf * 16] = acc[mf][nf][r];
  }
}

// K2: per (b,h) block of 512 threads. Reads hp (d_ws), writes out (d_out) —
// separate buffers, so the sweep may re-read V while other waves emit.
// Same verified math as R3/R4; the vreg[64] scratch array (runtime-indexed ->
// local memory, VGPR_Count=56 showed the spill) is replaced by a 2-deep
// rolling prefetch re-read of V in the sweep: addresses depend only on
// tpm[] (LDS), not on the scan chain, and emission work covers L2/L3 latency.
__global__ __launch_bounds__(512, 2) void k2_fused(
    const float* __restrict__ hp, const float* __restrict__ att,
    float* __restrict__ out) {
  __shared__ float tv[NA]; __shared__ int tpm[NA];
  __shared__ float sv[NA]; __shared__ int spm[NA];
  __shared__ float wp[NA]; __shared__ float wn[NA];
  __shared__ float rawP8[NW * 64]; __shared__ float rawN8[NW * 64];
  __shared__ float sufPc[(NW + 1) * 64]; __shared__ float preNc[(NW + 1) * 64];
  __shared__ float zps[NA + 1]; __shared__ float znp[NA + 1];
  __shared__ float szP[NC]; __shared__ float szN[NC];
  __shared__ float sufZ[NC + 1]; __shared__ float preZ[NC + 1];
  __shared__ float4 abi[NA];   // {A, B, 1/den, orig_row} per s-rank
  __shared__ int jsr[NA];      // js per s-rank (non-increasing)
  __shared__ int Earr[NA];     // E[j] = first rank with js <= j
  __shared__ float asrc[HD]; __shared__ float adst[HD];

  int bh = blockIdx.x;
  int head = bh & (NH - 1);
  int t = threadIdx.x;
  int lane = t & 63, w = t >> 6;
  const float* vbase = hp + (size_t)bh * NA * HD;

  if (t < 2 * HD) {
    float a = att[head * 2 * HD + t];
    if (t < HD) asrc[t] = a; else adst[t - HD] = a;
  }
  __syncthreads();

  // ---- s,t row-dots: thread t = natural row t (float4 loads, L3-hot) ----
  float vt, vs; int it = t, is_ = t;
  {
    const float4* vr = (const float4*)(vbase + (size_t)t * HD);
    float s0 = 0.f, s1 = 0.f, t0 = 0.f, t1 = 0.f;
    #pragma unroll
    for (int j = 0; j < HD / 4; j += 2) {
      float4 v0 = vr[j], v1 = vr[j + 1];
      s0 += v0.x*asrc[4*j+0] + v0.y*asrc[4*j+1] + v0.z*asrc[4*j+2] + v0.w*asrc[4*j+3];
      t0 += v0.x*adst[4*j+0] + v0.y*adst[4*j+1] + v0.z*adst[4*j+2] + v0.w*adst[4*j+3];
      s1 += v1.x*asrc[4*j+4] + v1.y*asrc[4*j+5] + v1.z*asrc[4*j+6] + v1.w*asrc[4*j+7];
      t1 += v1.x*adst[4*j+4] + v1.y*adst[4*j+5] + v1.z*adst[4*j+6] + v1.w*adst[4*j+7];
    }
    vs = s0 + s1; vt = t0 + t1;
  }

  // ---- dual hybrid bitonic sort (t asc, s asc), value+index in regs ----
  for (int size = 2; size <= NA; size <<= 1) {
    bool dirAsc = ((t & size) == 0);
    for (int stride = size >> 1; stride > 0; stride >>= 1) {
      float pt, ps; int pit, pis;
      if (stride >= 64) {
        tv[t] = vt; tpm[t] = it; sv[t] = vs; spm[t] = is_;
        __syncthreads();
        pt = tv[t ^ stride]; pit = tpm[t ^ stride];
        ps = sv[t ^ stride]; pis = spm[t ^ stride];
        __syncthreads();
      } else {
        pt = __shfl_xor(vt, stride, 64); pit = __shfl_xor(it, stride, 64);
        ps = __shfl_xor(vs, stride, 64); pis = __shfl_xor(is_, stride, 64);
      }
      bool mn = (((t & stride) == 0) == dirAsc);
      if (mn ? (pt < vt) : (pt > vt)) { vt = pt; it = pit; }
      if (mn ? (ps < vs) : (ps > vs)) { vs = ps; is_ = pis; }
    }
  }
  tv[t] = vt; tpm[t] = it; sv[t] = vs; spm[t] = is_;
  __syncthreads();

  float cmax = fmaxf(tv[NA - 1], 0.f);
  float amax = fmaxf(sv[NA - 1], 0.f);
  wp[t] = __expf(vt - cmax);
  wn[t] = __expf(NEG * vt - cmax);
  __syncthreads();

  // ---- phase A: wave w reads its 64 sorted V rows, weighted seed sums ----
  {
    float aP = 0.f, aN = 0.f;
    #pragma unroll
    for (int jj = 0; jj < 64; ++jj) {
      int j = (w << 6) + jj;
      float vv = vbase[(size_t)tpm[j] * HD + lane];
      aP += wp[j] * vv;
      aN += wn[j] * vv;
    }
    rawP8[(w << 6) + lane] = aP;
    rawN8[(w << 6) + lane] = aN;
  }
  __syncthreads();

  // ---- cross-wave scans (vector, G=64) + scalar chunk sums (G=16) ----
  if (t < 64) {
    int d = t; float run = 0.f;
    sufPc[NW * 64 + d] = 0.f;
    for (int ww = NW - 1; ww >= 0; --ww) {
      run += rawP8[ww * 64 + d]; sufPc[ww * 64 + d] = run;
    }
  } else if (t < 128) {
    int d = t - 64; float run = 0.f;
    for (int ww = 0; ww <= NW; ++ww) {
      preNc[ww * 64 + d] = run;
      if (ww < NW) run += rawN8[ww * 64 + d];
    }
  } else if (t < 160) {
    int c = t - 128; float a = 0.f;
    for (int j = c * CH; j < c * CH + CH; ++j) a += wp[j];
    szP[c] = a;
  } else if (t < 192) {
    int c = t - 160; float a = 0.f;
    for (int j = c * CH; j < c * CH + CH; ++j) a += wn[j];
    szN[c] = a;
  }
  __syncthreads();

  if (t == 0) {
    float run = 0.f; sufZ[NC] = 0.f;
    for (int cc = NC - 1; cc >= 0; --cc) { run += szP[cc]; sufZ[cc] = run; }
  } else if (t == 1) {
    float run = 0.f;
    for (int cc = 0; cc <= NC; ++cc) { preZ[cc] = run; if (cc < NC) run += szN[cc]; }
  }
  __syncthreads();

  // ---- full-resolution scalar denominator tables ----
  {
    int ch = t >> 4;
    float a = 0.f;
    for (int k = t; k < ch * CH + CH; ++k) a += wp[k];
    zps[t] = a + sufZ[ch + 1];
    float b2 = 0.f;
    for (int k = ch * CH; k < t; ++k) b2 += wn[k];
    znp[t] = preZ[ch] + b2;
    if (t == 0) { zps[NA] = 0.f; znp[NA] = preZ[NC]; }
  }
  __syncthreads();

  // ---- per-rank info: thread t = s-rank t (holds vs, is_ in regs) ----
  {
    float A = __expf(vs - amax);
    float B = __expf(NEG * vs - amax);
    float key = -vs;
    int lo = 0, hi = NA;
    while (lo < hi) { int mid = (lo + hi) >> 1; if (tv[mid] < key) lo = mid + 1; else hi = mid; }
    float den = A * zps[lo] + B * znp[lo];
    float4 qv; qv.x = A; qv.y = B; qv.z = 1.f / den; qv.w = __int_as_float(is_);
    abi[t] = qv;
    jsr[t] = lo;
  }
  __syncthreads();

  // ---- E[j]: first rank with jsr <= j (jsr sorted descending) ----
  {
    int lo = 0, hi = NA;
    while (lo < hi) { int mid = (lo + hi) >> 1; if (jsr[mid] > t) lo = mid + 1; else hi = mid; }
    Earr[t] = lo;
  }
  __syncthreads();

  // ---- ascending sweep, V re-read with 2-deep rolling prefetch ----
  {
    float sufPv = sufPc[w * 64 + lane];      // suffix incl. this wave's rows
    float preSeedN = preNc[w * 64 + lane];   // exact prefix before this wave
    float runN = 0.f;
    size_t obase = (size_t)bh * NA * HD + lane;
    int jb = w << 6;
    int eprev = (w == 0) ? NA : Earr[jb - 1];   // E[j-1] carried
    float vv0 = vbase[(size_t)tpm[jb] * HD + lane];
    float vv1 = vbase[(size_t)tpm[jb + 1] * HD + lane];
    #pragma unroll 1
    for (int jj = 0; jj < 64; ++jj) {
      int j = jb + jj;
      float vv = vv0;
      vv0 = vv1;
      if (jj < 62) vv1 = vbase[(size_t)tpm[j + 2] * HD + lane];
      int ecur = Earr[j];
      float preNv = preSeedN + runN;
      for (int r = ecur; r < eprev; ++r) {   // ranks with js == j
        float4 qv = abi[r];
        float x = (qv.x * sufPv + qv.y * preNv) * qv.z;
        int orow = __float_as_int(qv.w);
        out[obase + (size_t)orow * HD] = x > 0.f ? x : __expf(x) - 1.f;
      }
      sufPv -= wp[j] * vv;
      runN  += wn[j] * vv;
      eprev = ecur;
    }
    if (w == NW - 1) {                       // group js == 512: [0, E[511])
      float preNv = preSeedN + runN;         // == total N prefix
      for (int r = 0; r < eprev; ++r) {
        float4 qv = abi[r];
        float x = (qv.y * preNv) * qv.z;     // sufP[512] == 0
        int orow = __float_as_int(qv.w);
        out[obase + (size_t)orow * HD] = x > 0.f ? x : __expf(x) - 1.f;
      }
    }
  }
}

extern "C" void kernel_launch(void* const* d_in, const int* in_sizes, int n_in,
                              void* d_out, int out_size, void* d_ws, size_t ws_size,
                              hipStream_t stream) {
  const float* h   = (const float*)d_in[0];
  const float* W   = (const float*)d_in[1];
  const float* att = (const float*)d_in[2];
  float* out = (float*)d_out;
  float* hp  = (float*)d_ws;   // 33.5 MB needed; ws is 256 MiB (poison-filled
                               // every iter regardless of use — R3 evidence)

  k1_mfma <<<dim3(1024),    dim3(256), 0, stream>>>(h, W, hp);
  k2_fused<<<dim3(BS * NH), dim3(512), 0, stream>>>(hp, att, out);
}